// Round 6
// baseline (92.959 us; speedup 1.0000x reference)
//
#include <hip/hip_runtime.h>

static constexpr int IH = 480;
static constexpr int IW = 640;
static constexpr int IHW = IH * IW;

typedef float f32x4  __attribute__((ext_vector_type(4)));
typedef float f32x4u __attribute__((ext_vector_type(4), aligned(4)));  // 4B-aligned vector load

// 8 (axis, dir) combos in reference order: ud d1/d2, lr d1/d2, lu d1/d2, ld d1/d2
__device__ __constant__ const int c_oy[8] = { -1, +1,  0,  0, -1, +1, -1, +1 };
__device__ __constant__ const int c_ox[8] = {  0,  0, -1, +1, -1, +1, +1, -1 };

__global__ __launch_bounds__(256) void prop_kernel(
    const float* __restrict__ depth,
    const float* __restrict__ normal,
    const float* __restrict__ rgb,
    const float* __restrict__ conf,
    const float* __restrict__ Kinv,
    float* __restrict__ out)
{
    const int q  = blockIdx.y;          // output plane 0..119
    const int bi = blockIdx.z;          // batch
    const int c  = q / 5;               // combo 0..23
    const int ch = q - c * 5;           // channel: 0=depth, 1=conf, 2..4=rgb
    const int oi = c >> 3;
    const int k  = c & 7;
    const int o  = 2 * oi + 1;          // 1, 3, 5
    const int oy = c_oy[k] * o;
    const int ox = c_ox[k] * o;

    const int p0 = (blockIdx.x * 256 + threadIdx.x) * 4;  // 4 consecutive px, same row
    const int y  = p0 / IW;
    const int x0 = p0 - y * IW;
    const int sy = y + oy;

    const bool rowin   = (sy >= 0) & (sy < IH);
    const bool fullcol = (x0 + ox >= 0) & (x0 + 3 + ox < IW);

    float* ob = out + (((size_t)bi * 24 + c) * 5 + ch) * IHW + p0;

    if (ch != 0) {
        // shifted-memcpy channel: conf or one rgb plane, zero-filled outside
        const float* sp = (ch == 1) ? (conf + (size_t)bi * IHW)
                                    : (rgb + ((size_t)bi * 3 + (ch - 2)) * IHW);
        f32x4 v;
        if (rowin & fullcol) {
            v = *reinterpret_cast<const f32x4u*>(sp + sy * IW + x0 + ox);
        } else if (rowin) {
#pragma unroll
            for (int i = 0; i < 4; ++i) {
                const int sx = x0 + i + ox;
                v[i] = (sx >= 0 && sx < IW) ? sp[sy * IW + sx] : 0.0f;
            }
        } else {
            v = (f32x4)0.0f;
        }
        __builtin_nontemporal_store(v, reinterpret_cast<f32x4*>(ob));
        return;
    }

    // depth channel
    const float* dp = depth  + (size_t)bi * IHW;
    const float* nr = normal + (size_t)bi * 3 * IHW;

    const float* Ki = Kinv + bi * 9;
    const float k00 = Ki[0], k01 = Ki[1], k02 = Ki[2];
    const float k10 = Ki[3], k11 = Ki[4], k12 = Ki[5];
    const float k20 = Ki[6], k21 = Ki[7], k22 = Ki[8];

    const float fy  = (float)y;
    const float fox = (float)ox, foy = (float)oy;
    const float e0  = fox * k00 + foy * k01;   // K_inv * (ox, oy, 0)
    const float e1  = fox * k10 + foy * k11;
    const float e2  = fox * k20 + foy * k21;

    f32x4 v;
    if (rowin & fullcol) {
        const int spi = sy * IW + x0 + ox;
        const f32x4 ds = *reinterpret_cast<const f32x4u*>(dp + spi);
        const f32x4 n0 = *reinterpret_cast<const f32x4u*>(nr + spi);
        const f32x4 n1 = *reinterpret_cast<const f32x4u*>(nr + IHW + spi);
        const f32x4 n2 = *reinterpret_cast<const f32x4u*>(nr + 2 * IHW + spi);
#pragma unroll
        for (int i = 0; i < 4; ++i) {
            const float fx = (float)(x0 + i);
            const float r0 = k00 * fx + k01 * fy + k02;   // ray at dest pixel
            const float r1 = k10 * fx + k11 * fy + k12;
            const float r2 = k20 * fx + k21 * fy + k22;
            const float den = n0[i] * r0 + n1[i] * r1 + n2[i] * r2;
            const float t   = den + n0[i] * e0 + n1[i] * e1 + n2[i] * e2;
            const float w   = ds[i] * t * __builtin_amdgcn_rcpf(den + 1e-18f);
            v[i] = fminf(fmaxf(w, 0.01f), 10.0f);
        }
    } else if (rowin) {
#pragma unroll
        for (int i = 0; i < 4; ++i) {
            const int sx = x0 + i + ox;
            if (sx >= 0 && sx < IW) {
                const int sp = sy * IW + sx;
                const float n0 = nr[sp];
                const float n1 = nr[IHW + sp];
                const float n2 = nr[2 * IHW + sp];
                const float fx = (float)(x0 + i);
                const float r0 = k00 * fx + k01 * fy + k02;
                const float r1 = k10 * fx + k11 * fy + k12;
                const float r2 = k20 * fx + k21 * fy + k22;
                const float den = n0 * r0 + n1 * r1 + n2 * r2;
                const float t   = den + n0 * e0 + n1 * e1 + n2 * e2;
                const float w   = dp[sp] * t * __builtin_amdgcn_rcpf(den + 1e-18f);
                v[i] = fminf(fmaxf(w, 0.01f), 10.0f);
            } else {
                v[i] = dp[p0 + i];   // boundary pass-through
            }
        }
    } else {
#pragma unroll
        for (int i = 0; i < 4; ++i) {
            const int sx = x0 + i + ox;
            // ld-d2 quirk: bottom boundary passes depth[y, x-o] through
            if (k == 7 && sy >= IH && sx >= 0) v[i] = dp[y * IW + sx];
            else                               v[i] = dp[p0 + i];
        }
    }
    __builtin_nontemporal_store(v, reinterpret_cast<f32x4*>(ob));
}

extern "C" void kernel_launch(void* const* d_in, const int* in_sizes, int n_in,
                              void* d_out, int out_size, void* d_ws, size_t ws_size,
                              hipStream_t stream) {
    const float* depth  = (const float*)d_in[0];
    const float* normal = (const float*)d_in[1];
    const float* rgb    = (const float*)d_in[2];
    const float* conf   = (const float*)d_in[3];
    const float* Kinv   = (const float*)d_in[4];
    float* out = (float*)d_out;

    const int B = in_sizes[0] / IHW;
    dim3 grid(IHW / (256 * 4), 120, B);   // 300 x-blocks, one plane per y-block
    dim3 block(256, 1, 1);

    hipLaunchKernelGGL(prop_kernel, grid, block, 0, stream,
                       depth, normal, rgb, conf, Kinv, out);
}